// Round 12
// baseline (232.511 us; speedup 1.0000x reference)
//
#include <hip/hip_runtime.h>
#include <cstdint>
#include <cstddef>

#define N_NODES 50000
#define N_EDGES 800000
#define ROWS_PAD 50048  // 1564 tiles * 32 rows; pad rows: deg 0, stores guarded
#define ZROW 50000      // dedicated all-zero fp8 row for ragged-degree padding
#define BUCKET_CAP 64   // Poisson(16) max degree over 50K nodes ~45; P(>64) ~ 1e-18

typedef _Float16 f16;
typedef _Float16 f16x2 __attribute__((ext_vector_type(2)));
typedef _Float16 f16x8 __attribute__((ext_vector_type(8)));
typedef float f32x2 __attribute__((ext_vector_type(2)));
typedef float f32x4 __attribute__((ext_vector_type(4)));
typedef float fx4 __attribute__((ext_vector_type(4)));
typedef unsigned int u32x2 __attribute__((ext_vector_type(2)));
typedef unsigned short us4 __attribute__((ext_vector_type(4)));

// ---------------- fused preprocessing (one dispatch, block-range split) --------
// Fill is dst-range partitioned 16-way (blockIdx&15). No NT hints (round-10:
// NT loads killed the L2-warm edge re-scan, NT stores evicted X8 before
// layer1's gathers, +16 us). All features live as fp8 e4m3 only (X8/H8):
// round-12 removes the f16 root tables entirely -- both GEMM A-halves decode
// fp8 in-register.

#define NRANGE 16
#define EPT 16
#define CHUNK (256 * EPT)                       // 4096 edges
#define NCHUNK ((N_EDGES + CHUNK - 1) / CHUNK)  // 196
#define NB_FILL (NCHUNK * NRANGE)               // 3136
#define NB_CX 3125                              // 50000*16 threads, 8 fp8 each
#define NB_CW 192                               // (128*256 + 64*256) / 256
#define RANGE_SZ (N_NODES / NRANGE)             // 3125

__global__ __launch_bounds__(256) void preprocess_kernel(
    const int* __restrict__ edge, int* __restrict__ cnt, unsigned short* __restrict__ bucket,
    const float* __restrict__ x, unsigned char* __restrict__ X8, unsigned char* __restrict__ H8,
    const float* __restrict__ Wl1, const float* __restrict__ Wr1,
    const float* __restrict__ Wl2, const float* __restrict__ Wr2,
    f16* __restrict__ Wc1, f16* __restrict__ Wc2) {
  const int b = blockIdx.x;
  const int tid = threadIdx.x;
  if (b < NB_FILL) {
    const int r = b & (NRANGE - 1), chunk = b >> 4;
    const int lo = r * RANGE_SZ, hi = lo + RANGE_SZ;
    const int base = chunk * CHUNK + tid;
    #pragma unroll
    for (int i = 0; i < EPT; ++i) {
      const int e = base + i * 256;
      if (e < N_EDGES) {
        const int dst = edge[N_EDGES + e];
        if (dst >= lo && dst < hi) {
          const int src = edge[e];
          const int pos = atomicAdd(&cnt[dst], 1);
          if (pos < BUCKET_CAP) bucket[(size_t)dst * BUCKET_CAP + pos] = (unsigned short)src;
        }
      }
    }
  } else if (b < NB_FILL + NB_CX) {
    const int idx = (b - NB_FILL) * 256 + tid;  // < 800000 exact
    const int row = idx >> 4, c8 = idx & 15;
    const fx4 v0 = *reinterpret_cast<const fx4*>(x + (size_t)row * 128 + c8 * 8);
    const fx4 v1 = *reinterpret_cast<const fx4*>(x + (size_t)row * 128 + c8 * 8 + 4);
    u32x2 p;
    int w = __builtin_amdgcn_cvt_pk_fp8_f32(v0[0], v0[1], 0, false);
    w = __builtin_amdgcn_cvt_pk_fp8_f32(v0[2], v0[3], w, true);
    p[0] = (unsigned int)w;
    w = __builtin_amdgcn_cvt_pk_fp8_f32(v1[0], v1[1], 0, false);
    w = __builtin_amdgcn_cvt_pk_fp8_f32(v1[2], v1[3], w, true);
    p[1] = (unsigned int)w;
    *reinterpret_cast<u32x2*>(X8 + (size_t)row * 128 + c8 * 8) = p;
  } else if (b < NB_FILL + NB_CX + NB_CW) {
    const int idx = (b - NB_FILL - NB_CX) * 256 + tid;  // < 49152 exact
    // Wc[n][k] = k<128 ? Wl[n][k] : Wr[n][k-128]
    if (idx < 128 * 256) {
      const int n = idx >> 8, k = idx & 255;
      Wc1[idx] = (f16)((k < 128) ? Wl1[n * 128 + k] : Wr1[n * 128 + (k - 128)]);
    } else {
      const int j = idx - 128 * 256;
      const int n = j >> 8, k = j & 255;
      Wc2[j] = (f16)((k < 128) ? Wl2[n * 128 + k] : Wr2[n * 128 + (k - 128)]);
    }
  } else {
    // zero both ZROW fp8 rows (gather padding target; fp8 zero = 0x00)
    if (tid < 32)
      reinterpret_cast<unsigned int*>(X8 + (size_t)ZROW * 128)[tid] = 0u;
    else if (tid < 64)
      reinterpret_cast<unsigned int*>(H8 + (size_t)ZROW * 128)[tid - 32] = 0u;
  }
}

// ---- fp8x8 (u32x2) -> f16x8 decode ----
__device__ __forceinline__ f16x8 decode8(u32x2 v) {
  const f32x2 f0 = __builtin_amdgcn_cvt_pk_f32_fp8((int)v[0], false);
  const f32x2 f1 = __builtin_amdgcn_cvt_pk_f32_fp8((int)v[0], true);
  const f32x2 f2 = __builtin_amdgcn_cvt_pk_f32_fp8((int)v[1], false);
  const f32x2 f3 = __builtin_amdgcn_cvt_pk_f32_fp8((int)v[1], true);
  f16x8 a;
  a[0] = (f16)f0[0]; a[1] = (f16)f0[1]; a[2] = (f16)f1[0]; a[3] = (f16)f1[1];
  a[4] = (f16)f2[0]; a[5] = (f16)f2[1]; a[6] = (f16)f3[0]; a[7] = (f16)f3[1];
  return a;
}

// ---------------- aggregate: 32 nodes/block (2 quad-groups/wave) -> LDS means --
// fp8 gather, 32-DEEP batch: md = max degree of the 4 nodes ~24 avg, so one
// 32-batch covers 84% of groups in a single latency stall (round-11: 16-deep
// paid the ~300-900cy L3 stall twice). v[32] = 64 VGPRs, audited against the
// launch_bounds(256,4)=128 cap -- genuinely in flight (round-7 lesson).
// M rows padded to 136 f16 -> 2-way bank aliasing only (free, m136).

__device__ __forceinline__ void aggregate_to_lds(
    const unsigned char* __restrict__ F8, const int* __restrict__ cnt,
    const unsigned short* __restrict__ bucket,
    f16 (*M)[136], int wid, int lane) {
  const int quad = lane >> 4, l16 = lane & 15;
  #pragma unroll 1
  for (int g = 0; g < 2; ++g) {
    const int nb = blockIdx.x * 32 + wid * 8 + g * 4;
    const int node = nb + quad;
    const int dv = (lane < 4) ? cnt[nb + lane] : 0;
    const int dq = __shfl(dv, quad, 64);
    const int dqc = min(dq, BUCKET_CAP);
    int md = max(max(__shfl(dv, 0, 64), __shfl(dv, 1, 64)),
                 max(__shfl(dv, 2, 64), __shfl(dv, 3, 64)));
    md = min(md, BUCKET_CAP);
    // lane l16 of quad q holds bucket slots [4*l16, 4*l16+4) of node nb+q
    const us4 b4 = *reinterpret_cast<const us4*>(bucket + (size_t)node * BUCKET_CAP + l16 * 4);
    float acc[8];
    #pragma unroll
    for (int c = 0; c < 8; ++c) acc[c] = 0.f;
    const unsigned char* Fsrc = F8 + l16 * 8;
    for (int j = 0; j < md; j += 32) {
      u32x2 v[32];
      #pragma unroll
      for (int k = 0; k < 32; ++k) {
        const int slot = j + k;  // j%32==0 -> slot&3 == k&3
        const int idx = __shfl((int)b4[k & 3], quad * 16 + (slot >> 2), 64);
        const int row = (slot < dqc) ? idx : ZROW;  // ZROW zeroed, L1-hot
        v[k] = *reinterpret_cast<const u32x2*>(Fsrc + (size_t)row * 128);
      }
      #pragma unroll
      for (int k = 0; k < 32; ++k) {
        const f32x2 f0 = __builtin_amdgcn_cvt_pk_f32_fp8((int)v[k][0], false);
        const f32x2 f1 = __builtin_amdgcn_cvt_pk_f32_fp8((int)v[k][0], true);
        const f32x2 f2 = __builtin_amdgcn_cvt_pk_f32_fp8((int)v[k][1], false);
        const f32x2 f3 = __builtin_amdgcn_cvt_pk_f32_fp8((int)v[k][1], true);
        acc[0] += f0[0]; acc[1] += f0[1]; acc[2] += f1[0]; acc[3] += f1[1];
        acc[4] += f2[0]; acc[5] += f2[1]; acc[6] += f3[0]; acc[7] += f3[1];
      }
    }
    const float inv = 1.0f / (float)(dq > 0 ? dq : 1);
    f16x8 o;
    #pragma unroll
    for (int c = 0; c < 8; ++c) o[c] = (f16)(acc[c] * inv);
    *reinterpret_cast<f16x8*>(&M[wid * 8 + g * 4 + quad][l16 * 8]) = o;
  }
}

// ---------------- layer 1: aggregate + gemm  H8 = fp8(relu([mean|x]*Wc1^T+b)) --
// 32-row tile (R8-measured faster than 16-row), 4 waves: wave w -> rows
// (w&1)*16..+16, N-tiles (w>>1)*4..+4. K=256: k<128 A-frag from LDS means,
// k>=128 decoded from X8 own-row fp8 (prefetched BEFORE the aggregate so the
// load latency overlaps the gather). D: row = quad*4+r, col = lane&15.

__global__ __launch_bounds__(256, 4) void layer1_kernel(
    const unsigned char* __restrict__ X8,
    const int* __restrict__ cnt, const unsigned short* __restrict__ bucket,
    const f16* __restrict__ Wc, const float* __restrict__ bias,
    unsigned char* __restrict__ H8) {
  __shared__ f16 M[32][136];
  const int wid = threadIdx.x >> 6, lane = threadIdx.x & 63;
  const int quad = lane >> 4, l16 = lane & 15;
  const int rhalf = wid & 1, nhalf = wid >> 1;
  const int row0 = blockIdx.x * 32 + rhalf * 16;
  // prefetch own-row fp8 roots (valid memory through ROWS_PAD; stores guarded)
  const unsigned char* Xrow = X8 + (size_t)(row0 + l16) * 128 + quad * 8;
  u32x2 rr[4];
  #pragma unroll
  for (int s2 = 0; s2 < 4; ++s2)
    rr[s2] = *reinterpret_cast<const u32x2*>(Xrow + s2 * 32);
  aggregate_to_lds(X8, cnt, bucket, M, wid, lane);
  __syncthreads();
  f32x4 acc[4];
  #pragma unroll
  for (int t = 0; t < 4; ++t) acc[t] = (f32x4){0.f, 0.f, 0.f, 0.f};
  const f16x8* Wb = reinterpret_cast<const f16x8*>(Wc) + quad;
  #pragma unroll
  for (int s = 0; s < 8; ++s) {
    const f16x8 a = (s < 4)
        ? *reinterpret_cast<const f16x8*>(&M[rhalf * 16 + l16][quad * 8 + s * 32])
        : decode8(rr[s - 4]);
    #pragma unroll
    for (int t = 0; t < 4; ++t) {
      const int u = nhalf * 4 + t;
      const f16x8 bb = Wb[(u * 16 + l16) * 32 + s * 4];
      acc[t] = __builtin_amdgcn_mfma_f32_16x16x32_f16(a, bb, acc[t], 0, 0, 0);
    }
  }
  #pragma unroll
  for (int t = 0; t < 4; ++t) {
    const int col = (nhalf * 4 + t) * 16 + l16;
    const float bv = bias[col];
    #pragma unroll
    for (int r = 0; r < 4; ++r) {
      const int row = row0 + quad * 4 + r;
      if (row < N_NODES) {
        const float vv = fmaxf(acc[t][r] + bv, 0.f);
        const int p = __builtin_amdgcn_cvt_pk_fp8_f32(vv, vv, 0, false);
        H8[(size_t)row * 128 + col] = (unsigned char)(p & 0xFF);
      }
    }
  }
}

// ---------------- layer 2: aggregate + gemm + relu + log_softmax ---------------
// 32-row tile: wave w -> rows (w&1)*16, N-tiles (w>>1)*2..+2 (of 4). Roots
// decoded from H8 fp8 (prefetched). Softmax row spans waves w and w^2 ->
// LDS partial max/sum combine (PM/PS).

__global__ __launch_bounds__(256, 4) void layer2_kernel(
    const unsigned char* __restrict__ H8,
    const int* __restrict__ cnt, const unsigned short* __restrict__ bucket,
    const f16* __restrict__ Wc, const float* __restrict__ bias,
    float* __restrict__ out) {
  __shared__ f16 M[32][136];
  __shared__ float PM[4][16], PS[4][16];
  const int wid = threadIdx.x >> 6, lane = threadIdx.x & 63;
  const int quad = lane >> 4, l16 = lane & 15;
  const int rhalf = wid & 1, nhalf = wid >> 1;
  const int row0 = blockIdx.x * 32 + rhalf * 16;
  const unsigned char* Hrow = H8 + (size_t)(row0 + l16) * 128 + quad * 8;
  u32x2 rr[4];
  #pragma unroll
  for (int s2 = 0; s2 < 4; ++s2)
    rr[s2] = *reinterpret_cast<const u32x2*>(Hrow + s2 * 32);
  aggregate_to_lds(H8, cnt, bucket, M, wid, lane);
  __syncthreads();
  f32x4 acc[2];
  #pragma unroll
  for (int t = 0; t < 2; ++t) acc[t] = (f32x4){0.f, 0.f, 0.f, 0.f};
  const f16x8* Wb = reinterpret_cast<const f16x8*>(Wc) + quad;
  #pragma unroll
  for (int s = 0; s < 8; ++s) {
    const f16x8 a = (s < 4)
        ? *reinterpret_cast<const f16x8*>(&M[rhalf * 16 + l16][quad * 8 + s * 32])
        : decode8(rr[s - 4]);
    #pragma unroll
    for (int t = 0; t < 2; ++t) {
      const int u = nhalf * 2 + t;
      const f16x8 bb = Wb[(u * 16 + l16) * 32 + s * 4];
      acc[t] = __builtin_amdgcn_mfma_f32_16x16x32_f16(a, bb, acc[t], 0, 0, 0);
    }
  }
  float bv[2];
  #pragma unroll
  for (int t = 0; t < 2; ++t) bv[t] = bias[(nhalf * 2 + t) * 16 + l16];
  float v[4][2], pm[4], ps[4];
  #pragma unroll
  for (int r = 0; r < 4; ++r) {
    #pragma unroll
    for (int t = 0; t < 2; ++t) v[r][t] = fmaxf(acc[t][r] + bv[t], 0.f);
    float m = fmaxf(v[r][0], v[r][1]);
    #pragma unroll
    for (int off = 1; off < 16; off <<= 1) m = fmaxf(m, __shfl_xor(m, off, 64));
    float s = __expf(v[r][0] - m) + __expf(v[r][1] - m);
    #pragma unroll
    for (int off = 1; off < 16; off <<= 1) s += __shfl_xor(s, off, 64);
    pm[r] = m;
    ps[r] = s;
  }
  if (l16 == 0) {
    #pragma unroll
    for (int r = 0; r < 4; ++r) {
      PM[wid][quad * 4 + r] = pm[r];
      PS[wid][quad * 4 + r] = ps[r];
    }
  }
  __syncthreads();
  #pragma unroll
  for (int r = 0; r < 4; ++r) {
    const float m2 = PM[wid ^ 2][quad * 4 + r];
    const float s2 = PS[wid ^ 2][quad * 4 + r];
    const float mt = fmaxf(pm[r], m2);
    const float st = ps[r] * __expf(pm[r] - mt) + s2 * __expf(m2 - mt);
    const float ls = mt + __logf(st);
    const int row = row0 + quad * 4 + r;
    if (row < N_NODES) {
      #pragma unroll
      for (int t = 0; t < 2; ++t)
        out[(size_t)row * 64 + (nhalf * 2 + t) * 16 + l16] = v[r][t] - ls;
    }
  }
}

// ---------------- launch ----------------

extern "C" void kernel_launch(void* const* d_in, const int* in_sizes, int n_in,
                              void* d_out, int out_size, void* d_ws, size_t ws_size,
                              hipStream_t stream) {
  const float* x   = (const float*)d_in[0];
  const int* edge  = (const int*)d_in[1];  // [2][N_EDGES] int32
  const float* Wl1 = (const float*)d_in[2];
  const float* bl1 = (const float*)d_in[3];
  const float* Wr1 = (const float*)d_in[4];
  const float* Wl2 = (const float*)d_in[5];
  const float* bl2 = (const float*)d_in[6];
  const float* Wr2 = (const float*)d_in[7];
  float* out = (float*)d_out;

  char* ws = (char*)d_ws;
  size_t off = 0;
  auto alloc = [&](size_t bytes) -> char* {
    char* p = ws + off;
    off = (off + bytes + 255) & ~(size_t)255;
    return p;
  };
  int* cnt               = (int*)alloc((size_t)ROWS_PAD * 4);
  unsigned short* bucket = (unsigned short*)alloc((size_t)ROWS_PAD * BUCKET_CAP * 2);
  unsigned char* X8  = (unsigned char*)alloc((size_t)ROWS_PAD * 128); // x fp8
  unsigned char* H8  = (unsigned char*)alloc((size_t)ROWS_PAD * 128); // h fp8
  f16* Wc1           = (f16*)alloc((size_t)128 * 256 * 2);  // [Wl1 | Wr1] rows
  f16* Wc2           = (f16*)alloc((size_t)64 * 256 * 2);   // [Wl2 | Wr2] rows

  hipMemsetAsync(cnt, 0, (size_t)ROWS_PAD * 4, stream);

  preprocess_kernel<<<NB_FILL + NB_CX + NB_CW + 1, 256, 0, stream>>>(
      edge, cnt, bucket, x, X8, H8, Wl1, Wr1, Wl2, Wr2, Wc1, Wc2);

  layer1_kernel<<<ROWS_PAD / 32, 256, 0, stream>>>(X8, cnt, bucket, Wc1, bl1, H8);
  layer2_kernel<<<ROWS_PAD / 32, 256, 0, stream>>>(H8, cnt, bucket, Wc2, bl2, out);
}

// Round 13
// 207.719 us; speedup vs baseline: 1.1194x; 1.1194x over previous
//
#include <hip/hip_runtime.h>
#include <cstdint>
#include <cstddef>

#define N_NODES 50000
#define N_EDGES 800000
#define ROWS_PAD 50048  // 1564 tiles * 32 rows; pad rows: deg 0, stores guarded
#define ZROW 50000      // dedicated all-zero fp8 row for ragged-degree padding
#define BUCKET_CAP 64   // Poisson(16) max degree over 50K nodes ~45; P(>64) ~ 1e-18

typedef _Float16 f16;
typedef _Float16 f16x2 __attribute__((ext_vector_type(2)));
typedef _Float16 f16x8 __attribute__((ext_vector_type(8)));
typedef float f32x2 __attribute__((ext_vector_type(2)));
typedef float f32x4 __attribute__((ext_vector_type(4)));
typedef float fx4 __attribute__((ext_vector_type(4)));
typedef unsigned int u32x2 __attribute__((ext_vector_type(2)));
typedef unsigned short us4 __attribute__((ext_vector_type(4)));

// ---------------- fused preprocessing (one dispatch, block-range split) --------
// Fill is dst-range partitioned 8-WAY (blockIdx&7): R4 measured 43 us at 8-way
// vs R8's 58 us at 16-way (the 2x edge re-scan cost more than the finer bucket
// slices saved — R7's 16-way switch was never A/B'd; reverted). No NT hints
// (R10: NT loads killed the L2-warm edge re-scan, NT stores evicted X8 before
// layer1's gathers, +16 us).

#define NRANGE 8
#define EPT 16
#define CHUNK (256 * EPT)                       // 4096 edges
#define NCHUNK ((N_EDGES + CHUNK - 1) / CHUNK)  // 196
#define NB_FILL (NCHUNK * NRANGE)               // 1568
#define NB_CX 3125                              // 50000*16 threads, 8 elems each
#define NB_CW 192                               // (128*256 + 64*256) / 256
#define RANGE_SZ (N_NODES / NRANGE)             // 6250

__global__ __launch_bounds__(256) void preprocess_kernel(
    const int* __restrict__ edge, int* __restrict__ cnt, unsigned short* __restrict__ bucket,
    const float* __restrict__ x, f16* __restrict__ X16, unsigned char* __restrict__ X8,
    unsigned char* __restrict__ H8,
    const float* __restrict__ Wl1, const float* __restrict__ Wr1,
    const float* __restrict__ Wl2, const float* __restrict__ Wr2,
    f16* __restrict__ Wc1, f16* __restrict__ Wc2) {
  const int b = blockIdx.x;
  const int tid = threadIdx.x;
  if (b < NB_FILL) {
    const int r = b & (NRANGE - 1), chunk = b >> 3;
    const int lo = r * RANGE_SZ, hi = lo + RANGE_SZ;
    const int base = chunk * CHUNK + tid;
    #pragma unroll
    for (int i = 0; i < EPT; ++i) {
      const int e = base + i * 256;
      if (e < N_EDGES) {
        const int dst = edge[N_EDGES + e];
        if (dst >= lo && dst < hi) {
          const int src = edge[e];
          const int pos = atomicAdd(&cnt[dst], 1);
          if (pos < BUCKET_CAP) bucket[(size_t)dst * BUCKET_CAP + pos] = (unsigned short)src;
        }
      }
    }
  } else if (b < NB_FILL + NB_CX) {
    const int idx = (b - NB_FILL) * 256 + tid;  // < 800000 exact
    const int row = idx >> 4, c8 = idx & 15;
    const fx4 v0 = *reinterpret_cast<const fx4*>(x + (size_t)row * 128 + c8 * 8);
    const fx4 v1 = *reinterpret_cast<const fx4*>(x + (size_t)row * 128 + c8 * 8 + 4);
    // f16 root table (GEMM A right half)
    f16x8 o;
    o[0] = (f16)v0[0]; o[1] = (f16)v0[1]; o[2] = (f16)v0[2]; o[3] = (f16)v0[3];
    o[4] = (f16)v1[0]; o[5] = (f16)v1[1]; o[6] = (f16)v1[2]; o[7] = (f16)v1[3];
    *reinterpret_cast<f16x8*>(X16 + (size_t)row * 128 + c8 * 8) = o;
    // fp8 e4m3 gather table (mean path only)
    u32x2 p;
    int w = __builtin_amdgcn_cvt_pk_fp8_f32(v0[0], v0[1], 0, false);
    w = __builtin_amdgcn_cvt_pk_fp8_f32(v0[2], v0[3], w, true);
    p[0] = (unsigned int)w;
    w = __builtin_amdgcn_cvt_pk_fp8_f32(v1[0], v1[1], 0, false);
    w = __builtin_amdgcn_cvt_pk_fp8_f32(v1[2], v1[3], w, true);
    p[1] = (unsigned int)w;
    *reinterpret_cast<u32x2*>(X8 + (size_t)row * 128 + c8 * 8) = p;
  } else if (b < NB_FILL + NB_CX + NB_CW) {
    const int idx = (b - NB_FILL - NB_CX) * 256 + tid;  // < 49152 exact
    // Wc[n][k] = k<128 ? Wl[n][k] : Wr[n][k-128]
    if (idx < 128 * 256) {
      const int n = idx >> 8, k = idx & 255;
      Wc1[idx] = (f16)((k < 128) ? Wl1[n * 128 + k] : Wr1[n * 128 + (k - 128)]);
    } else {
      const int j = idx - 128 * 256;
      const int n = j >> 8, k = j & 255;
      Wc2[j] = (f16)((k < 128) ? Wl2[n * 128 + k] : Wr2[n * 128 + (k - 128)]);
    }
  } else {
    // zero both ZROW fp8 rows (gather padding target; fp8 zero = 0x00)
    if (tid < 32)
      reinterpret_cast<unsigned int*>(X8 + (size_t)ZROW * 128)[tid] = 0u;
    else if (tid < 64)
      reinterpret_cast<unsigned int*>(H8 + (size_t)ZROW * 128)[tid - 32] = 0u;
  }
}

// ---------------- aggregate: 32 nodes/block (2 quad-groups/wave) -> LDS means --
// fp8 gather, 16-deep batch (R12: 32-deep was defeated by regalloc — VGPR
// capped at 64, serialized, occupancy fell to 31%). Per instr: 64 lanes x 8B
// = 4 full 128B neighbor rows (one L2 line each). Decode v_cvt_pk_f32_fp8,
// accumulate fp32, write means to LDS as f16. M rows padded to 136 f16 ->
// 2-way bank aliasing only (free, m136).

__device__ __forceinline__ void aggregate_to_lds(
    const unsigned char* __restrict__ F8, const int* __restrict__ cnt,
    const unsigned short* __restrict__ bucket,
    f16 (*M)[136], int wid, int lane) {
  const int quad = lane >> 4, l16 = lane & 15;
  #pragma unroll 1
  for (int g = 0; g < 2; ++g) {
    const int nb = blockIdx.x * 32 + wid * 8 + g * 4;
    const int node = nb + quad;
    const int dv = (lane < 4) ? cnt[nb + lane] : 0;
    const int dq = __shfl(dv, quad, 64);
    const int dqc = min(dq, BUCKET_CAP);
    int md = max(max(__shfl(dv, 0, 64), __shfl(dv, 1, 64)),
                 max(__shfl(dv, 2, 64), __shfl(dv, 3, 64)));
    md = min(md, BUCKET_CAP);
    // lane l16 of quad q holds bucket slots [4*l16, 4*l16+4) of node nb+q
    const us4 b4 = *reinterpret_cast<const us4*>(bucket + (size_t)node * BUCKET_CAP + l16 * 4);
    float acc[8];
    #pragma unroll
    for (int c = 0; c < 8; ++c) acc[c] = 0.f;
    const unsigned char* Fsrc = F8 + l16 * 8;
    for (int j = 0; j < md; j += 16) {
      u32x2 v[16];
      #pragma unroll
      for (int k = 0; k < 16; ++k) {
        const int slot = j + k;  // j%16==0 -> slot&3 == k&3
        const int idx = __shfl((int)b4[k & 3], quad * 16 + (slot >> 2), 64);
        const int row = (slot < dqc) ? idx : ZROW;  // ZROW zeroed, L1-hot
        v[k] = *reinterpret_cast<const u32x2*>(Fsrc + (size_t)row * 128);
      }
      #pragma unroll
      for (int k = 0; k < 16; ++k) {
        const f32x2 f0 = __builtin_amdgcn_cvt_pk_f32_fp8((int)v[k][0], false);
        const f32x2 f1 = __builtin_amdgcn_cvt_pk_f32_fp8((int)v[k][0], true);
        const f32x2 f2 = __builtin_amdgcn_cvt_pk_f32_fp8((int)v[k][1], false);
        const f32x2 f3 = __builtin_amdgcn_cvt_pk_f32_fp8((int)v[k][1], true);
        acc[0] += f0[0]; acc[1] += f0[1]; acc[2] += f1[0]; acc[3] += f1[1];
        acc[4] += f2[0]; acc[5] += f2[1]; acc[6] += f3[0]; acc[7] += f3[1];
      }
    }
    const float inv = 1.0f / (float)(dq > 0 ? dq : 1);
    f16x8 o;
    #pragma unroll
    for (int c = 0; c < 8; ++c) o[c] = (f16)(acc[c] * inv);
    *reinterpret_cast<f16x8*>(&M[wid * 8 + g * 4 + quad][l16 * 8]) = o;
  }
}

// ---------------- layer 1: aggregate + gemm  H = relu([mean|x] * Wc1^T + b) ----
// 32-row tile (R8-measured best), 4 waves: wave w -> rows (w&1)*16..+16,
// N-tiles (w>>1)*4..+4. K=256: k<128 A-frag from LDS means, k>=128 from X16
// f16 roots (prefetched BEFORE the aggregate so load latency overlaps the
// gather). Epilogue: dual H16 f16 (coalesced full lines) + H8 fp8 (R12: H8-only
// byte stores caused partial-line RMW, WRITE 36 MB for 6.4 logical).

__global__ __launch_bounds__(256, 4) void layer1_kernel(
    const f16* __restrict__ X16, const unsigned char* __restrict__ X8,
    const int* __restrict__ cnt, const unsigned short* __restrict__ bucket,
    const f16* __restrict__ Wc, const float* __restrict__ bias,
    f16* __restrict__ H16, unsigned char* __restrict__ H8) {
  __shared__ f16 M[32][136];
  const int wid = threadIdx.x >> 6, lane = threadIdx.x & 63;
  const int quad = lane >> 4, l16 = lane & 15;
  const int rhalf = wid & 1, nhalf = wid >> 1;
  const int row0 = blockIdx.x * 32 + rhalf * 16;
  // prefetch own-row f16 roots (valid memory through ROWS_PAD; stores guarded)
  const f16* Xrow = X16 + (size_t)(row0 + l16) * 128 + quad * 8;
  f16x8 rr[4];
  #pragma unroll
  for (int s2 = 0; s2 < 4; ++s2)
    rr[s2] = *reinterpret_cast<const f16x8*>(Xrow + s2 * 32);
  aggregate_to_lds(X8, cnt, bucket, M, wid, lane);
  __syncthreads();
  f32x4 acc[4];
  #pragma unroll
  for (int t = 0; t < 4; ++t) acc[t] = (f32x4){0.f, 0.f, 0.f, 0.f};
  const f16x8* Wb = reinterpret_cast<const f16x8*>(Wc) + quad;
  #pragma unroll
  for (int s = 0; s < 8; ++s) {
    const f16x8 a = (s < 4)
        ? *reinterpret_cast<const f16x8*>(&M[rhalf * 16 + l16][quad * 8 + s * 32])
        : rr[s - 4];
    #pragma unroll
    for (int t = 0; t < 4; ++t) {
      const int u = nhalf * 4 + t;
      const f16x8 bb = Wb[(u * 16 + l16) * 32 + s * 4];
      acc[t] = __builtin_amdgcn_mfma_f32_16x16x32_f16(a, bb, acc[t], 0, 0, 0);
    }
  }
  #pragma unroll
  for (int t = 0; t < 4; ++t) {
    const int col = (nhalf * 4 + t) * 16 + l16;
    const float bv = bias[col];
    #pragma unroll
    for (int r = 0; r < 4; ++r) {
      const int row = row0 + quad * 4 + r;
      if (row < N_NODES) {
        const float vv = fmaxf(acc[t][r] + bv, 0.f);
        H16[(size_t)row * 128 + col] = (f16)vv;
        const int p = __builtin_amdgcn_cvt_pk_fp8_f32(vv, vv, 0, false);
        H8[(size_t)row * 128 + col] = (unsigned char)(p & 0xFF);
      }
    }
  }
}

// ---------------- layer 2: aggregate + gemm + relu + log_softmax ---------------
// 32-row tile: wave w -> rows (w&1)*16, N-tiles (w>>1)*2..+2 (of 4). Roots from
// H16 f16 (prefetched). Softmax row spans waves w and w^2 -> LDS PM/PS combine.

__global__ __launch_bounds__(256, 4) void layer2_kernel(
    const f16* __restrict__ H16, const unsigned char* __restrict__ H8,
    const int* __restrict__ cnt, const unsigned short* __restrict__ bucket,
    const f16* __restrict__ Wc, const float* __restrict__ bias,
    float* __restrict__ out) {
  __shared__ f16 M[32][136];
  __shared__ float PM[4][16], PS[4][16];
  const int wid = threadIdx.x >> 6, lane = threadIdx.x & 63;
  const int quad = lane >> 4, l16 = lane & 15;
  const int rhalf = wid & 1, nhalf = wid >> 1;
  const int row0 = blockIdx.x * 32 + rhalf * 16;
  const f16* Hrow = H16 + (size_t)(row0 + l16) * 128 + quad * 8;
  f16x8 rr[4];
  #pragma unroll
  for (int s2 = 0; s2 < 4; ++s2)
    rr[s2] = *reinterpret_cast<const f16x8*>(Hrow + s2 * 32);
  aggregate_to_lds(H8, cnt, bucket, M, wid, lane);
  __syncthreads();
  f32x4 acc[2];
  #pragma unroll
  for (int t = 0; t < 2; ++t) acc[t] = (f32x4){0.f, 0.f, 0.f, 0.f};
  const f16x8* Wb = reinterpret_cast<const f16x8*>(Wc) + quad;
  #pragma unroll
  for (int s = 0; s < 8; ++s) {
    const f16x8 a = (s < 4)
        ? *reinterpret_cast<const f16x8*>(&M[rhalf * 16 + l16][quad * 8 + s * 32])
        : rr[s - 4];
    #pragma unroll
    for (int t = 0; t < 2; ++t) {
      const int u = nhalf * 2 + t;
      const f16x8 bb = Wb[(u * 16 + l16) * 32 + s * 4];
      acc[t] = __builtin_amdgcn_mfma_f32_16x16x32_f16(a, bb, acc[t], 0, 0, 0);
    }
  }
  float bv[2];
  #pragma unroll
  for (int t = 0; t < 2; ++t) bv[t] = bias[(nhalf * 2 + t) * 16 + l16];
  float v[4][2], pm[4], ps[4];
  #pragma unroll
  for (int r = 0; r < 4; ++r) {
    #pragma unroll
    for (int t = 0; t < 2; ++t) v[r][t] = fmaxf(acc[t][r] + bv[t], 0.f);
    float m = fmaxf(v[r][0], v[r][1]);
    #pragma unroll
    for (int off = 1; off < 16; off <<= 1) m = fmaxf(m, __shfl_xor(m, off, 64));
    float s = __expf(v[r][0] - m) + __expf(v[r][1] - m);
    #pragma unroll
    for (int off = 1; off < 16; off <<= 1) s += __shfl_xor(s, off, 64);
    pm[r] = m;
    ps[r] = s;
  }
  if (l16 == 0) {
    #pragma unroll
    for (int r = 0; r < 4; ++r) {
      PM[wid][quad * 4 + r] = pm[r];
      PS[wid][quad * 4 + r] = ps[r];
    }
  }
  __syncthreads();
  #pragma unroll
  for (int r = 0; r < 4; ++r) {
    const float m2 = PM[wid ^ 2][quad * 4 + r];
    const float s2 = PS[wid ^ 2][quad * 4 + r];
    const float mt = fmaxf(pm[r], m2);
    const float st = ps[r] * __expf(pm[r] - mt) + s2 * __expf(m2 - mt);
    const float ls = mt + __logf(st);
    const int row = row0 + quad * 4 + r;
    if (row < N_NODES) {
      #pragma unroll
      for (int t = 0; t < 2; ++t)
        out[(size_t)row * 64 + (nhalf * 2 + t) * 16 + l16] = v[r][t] - ls;
    }
  }
}

// ---------------- launch ----------------

extern "C" void kernel_launch(void* const* d_in, const int* in_sizes, int n_in,
                              void* d_out, int out_size, void* d_ws, size_t ws_size,
                              hipStream_t stream) {
  const float* x   = (const float*)d_in[0];
  const int* edge  = (const int*)d_in[1];  // [2][N_EDGES] int32
  const float* Wl1 = (const float*)d_in[2];
  const float* bl1 = (const float*)d_in[3];
  const float* Wr1 = (const float*)d_in[4];
  const float* Wl2 = (const float*)d_in[5];
  const float* bl2 = (const float*)d_in[6];
  const float* Wr2 = (const float*)d_in[7];
  float* out = (float*)d_out;

  char* ws = (char*)d_ws;
  size_t off = 0;
  auto alloc = [&](size_t bytes) -> char* {
    char* p = ws + off;
    off = (off + bytes + 255) & ~(size_t)255;
    return p;
  };
  int* cnt               = (int*)alloc((size_t)ROWS_PAD * 4);
  unsigned short* bucket = (unsigned short*)alloc((size_t)ROWS_PAD * BUCKET_CAP * 2);
  f16* X16           = (f16*)alloc((size_t)ROWS_PAD * 128 * 2);       // x f16 roots
  f16* H16           = (f16*)alloc((size_t)ROWS_PAD * 128 * 2);       // h f16 roots
  unsigned char* X8  = (unsigned char*)alloc((size_t)ROWS_PAD * 128); // x fp8 gather
  unsigned char* H8  = (unsigned char*)alloc((size_t)ROWS_PAD * 128); // h fp8 gather
  f16* Wc1           = (f16*)alloc((size_t)128 * 256 * 2);  // [Wl1 | Wr1] rows
  f16* Wc2           = (f16*)alloc((size_t)64 * 256 * 2);   // [Wl2 | Wr2] rows

  hipMemsetAsync(cnt, 0, (size_t)ROWS_PAD * 4, stream);

  preprocess_kernel<<<NB_FILL + NB_CX + NB_CW + 1, 256, 0, stream>>>(
      edge, cnt, bucket, x, X16, X8, H8, Wl1, Wr1, Wl2, Wr2, Wc1, Wc2);

  layer1_kernel<<<ROWS_PAD / 32, 256, 0, stream>>>(X16, X8, cnt, bucket, Wc1, bl1, H16, H8);
  layer2_kernel<<<ROWS_PAD / 32, 256, 0, stream>>>(H8 ? H16 : H16, H8, cnt, bucket, Wc2, bl2, out);
}